// Round 8
// baseline (159.347 us; speedup 1.0000x reference)
//
#include <hip/hip_runtime.h>
#include <hip/hip_bf16.h>

#define NN 50000
#define EE 800000
#define DD 128
#define HH 8
#define CAP 64        // bucket capacity; P(deg>64) ~ 1e-55 for Binom(800K,1/50K)
#define KVS 256       // interleaved KV row stride (128 K + 128 V bf16)
#define CS 16         // counter stride: 1 counter per 64B line (cross-XCD fix)
#define QB 391        // ceil(50000/128) qkv blocks in mega
#define SB 782        // ceil(200000/256) scatter blocks in mega

typedef short bf16x8 __attribute__((ext_vector_type(8)));
typedef float f32x4 __attribute__((ext_vector_type(4)));
typedef unsigned short ushort8_t __attribute__((ext_vector_type(8)));

__device__ __forceinline__ unsigned short f2b(float f) {
    unsigned int u = __builtin_bit_cast(unsigned int, f);
    unsigned int r = (u + 0x7FFFu + ((u >> 16) & 1u)) >> 16;
    return (unsigned short)r;
}
__device__ __forceinline__ float b2f(unsigned short u) {
    return __builtin_bit_cast(float, ((unsigned int)u) << 16);
}

// ---------------- prep: convert 3 weight matrices to bf16 -----------------
__global__ __launch_bounds__(256) void prep(const float* __restrict__ Wq,
                                            const float* __restrict__ Wk,
                                            const float* __restrict__ Wv,
                                            unsigned short* __restrict__ Wqb,
                                            unsigned short* __restrict__ Wkb,
                                            unsigned short* __restrict__ Wvb) {
    int idx = blockIdx.x * 256 + threadIdx.x;  // ushort4 unit; 4096 per matrix
    int mat = idx >> 12;
    int off = idx & 4095;
    const float* src = (mat == 0) ? Wq : (mat == 1) ? Wk : Wv;
    unsigned short* dst = (mat == 0) ? Wqb : (mat == 1) ? Wkb : Wvb;
    float4 v = ((const float4*)src)[off];
    ushort4 o;
    o.x = f2b(v.x); o.y = f2b(v.y); o.z = f2b(v.z); o.w = f2b(v.w);
    ((ushort4*)dst)[off] = o;
}

// ---------------- qkv helper: one matrix, two 16-row groups ---------------
// A-frag: lane l -> x[rg0 + (l&15)][ (l>>4)*8 + s*32 + j ]
// B-frag: lane l -> W[c0*16 + (l&15)][ (l>>4)*8 + s*32 + j ]
// D:      row = (l>>4)*4 + reg, col = l&15
template <int OUTKIND>  // 0 = fp32 out (stride DD), 1 = bf16 into KV (stride KVS)
__device__ __forceinline__ void qkv_mat(const unsigned short* __restrict__ W,
                                        const float* __restrict__ bias,
                                        float* __restrict__ qo,
                                        unsigned short* __restrict__ kvo,
                                        int kvoff,
                                        const bf16x8 a[2][4],
                                        int r0, int mrow, int kb,
                                        bool act0, bool act1) {
#pragma unroll
    for (int c0 = 0; c0 < 8; ++c0) {
        float bval = bias[c0 * 16 + mrow];
        const unsigned short* wr = W + (size_t)(c0 * 16 + mrow) * DD + kb * 8;
        bf16x8 w0 = *(const bf16x8*)(wr);
        bf16x8 w1 = *(const bf16x8*)(wr + 32);
        bf16x8 w2 = *(const bf16x8*)(wr + 64);
        bf16x8 w3 = *(const bf16x8*)(wr + 96);
#pragma unroll
        for (int g = 0; g < 2; ++g) {
            bool act = (g == 0) ? act0 : act1;
            f32x4 acc = {bval, bval, bval, bval};
            acc = __builtin_amdgcn_mfma_f32_16x16x32_bf16(a[g][0], w0, acc, 0, 0, 0);
            acc = __builtin_amdgcn_mfma_f32_16x16x32_bf16(a[g][1], w1, acc, 0, 0, 0);
            acc = __builtin_amdgcn_mfma_f32_16x16x32_bf16(a[g][2], w2, acc, 0, 0, 0);
            acc = __builtin_amdgcn_mfma_f32_16x16x32_bf16(a[g][3], w3, acc, 0, 0, 0);
            if (act) {
                int orow = r0 + 16 * g + kb * 4;
                int col = c0 * 16 + mrow;
                if (OUTKIND == 0) {
#pragma unroll
                    for (int r = 0; r < 4; ++r)
                        qo[(size_t)(orow + r) * DD + col] = acc[r];
                } else {
#pragma unroll
                    for (int r = 0; r < 4; ++r)
                        kvo[(size_t)(orow + r) * KVS + kvoff + col] = f2b(acc[r]);
                }
            }
        }
    }
}

// ---------------- mega: qkv (blocks 0..QB-1) + bucket scatter (rest) ------
__global__ __launch_bounds__(256) void mega(
    const float* __restrict__ x,
    const unsigned short* __restrict__ Wq, const float* __restrict__ bq,
    const unsigned short* __restrict__ Wk, const float* __restrict__ bk,
    const unsigned short* __restrict__ Wv, const float* __restrict__ bv,
    const int* __restrict__ ei,
    float* __restrict__ Qo, unsigned short* __restrict__ KV,
    int* __restrict__ cnt, int* __restrict__ bucket) {
    if (blockIdx.x < QB) {
        // ---- QKV projection, no LDS, no barriers ----
        const int wave = threadIdx.x >> 6;
        const int l = threadIdx.x & 63;
        const int r0 = blockIdx.x * 128 + wave * 32;
        const int mrow = l & 15;
        const int kb = l >> 4;
        const bool act0 = (r0 < NN);       // 50000 % 16 == 0
        const bool act1 = (r0 + 16 < NN);
        if (!act0) return;

        bf16x8 a[2][4];
#pragma unroll
        for (int g = 0; g < 2; ++g) {
            int row = (g == 0 || act1) ? (r0 + 16 * g + mrow) : r0;
            const float* xr = x + (size_t)row * DD + kb * 8;
#pragma unroll
            for (int s = 0; s < 4; ++s) {
                float4 f0 = *(const float4*)(xr + s * 32);
                float4 f1 = *(const float4*)(xr + s * 32 + 4);
                bf16x8 t;
                t[0] = (short)f2b(f0.x); t[1] = (short)f2b(f0.y);
                t[2] = (short)f2b(f0.z); t[3] = (short)f2b(f0.w);
                t[4] = (short)f2b(f1.x); t[5] = (short)f2b(f1.y);
                t[6] = (short)f2b(f1.z); t[7] = (short)f2b(f1.w);
                a[g][s] = t;
            }
        }
        qkv_mat<0>(Wq, bq, Qo, (unsigned short*)nullptr, 0, a, r0, mrow, kb, act0, act1);
        qkv_mat<1>(Wk, bk, (float*)nullptr, KV, 0,   a, r0, mrow, kb, act0, act1);
        qkv_mat<1>(Wv, bv, (float*)nullptr, KV, 128, a, r0, mrow, kb, act0, act1);
    } else {
        // ---- bucket scatter with line-padded counters ----
        int e4 = (blockIdx.x - QB) * 256 + threadIdx.x;
        if (e4 < EE / 4) {
            int4 s = ((const int4*)ei)[e4];
            int4 d = ((const int4*)(ei + EE))[e4];
            int p;
            p = atomicAdd(&cnt[d.x * CS], 1); if (p < CAP) bucket[d.x * CAP + p] = s.x;
            p = atomicAdd(&cnt[d.y * CS], 1); if (p < CAP) bucket[d.y * CAP + p] = s.y;
            p = atomicAdd(&cnt[d.z * CS], 1); if (p < CAP) bucket[d.z * CAP + p] = s.z;
            p = atomicAdd(&cnt[d.w * CS], 1); if (p < CAP) bucket[d.w * CAP + p] = s.w;
        }
    }
}

// ---------------- gather: one wave per dst node, 4 edges in flight --------
// deg <= 64 => whole edge list in one wave-wide read.
// Lane l: edge slot es = l>>4, dim block q = l&15 (dims 8q..8q+7).
// Head = 16 dims = 2 lanes -> shfl_xor(.,1). Combine slots via xor 16,32.
__global__ __launch_bounds__(256) void gather4(const unsigned short* __restrict__ KV,
                                               const int* __restrict__ cnt,
                                               const int* __restrict__ bucket,
                                               float* __restrict__ qout) {
    int n = blockIdx.x * 4 + (threadIdx.x >> 6);
    if (n >= NN) return;
    int l = threadIdx.x & 63;
    int es = l >> 4;
    int q = l & 15;

    const float4* qrow = (const float4*)(qout + (size_t)n * DD + 8 * q);
    float4 qa = qrow[0], qb = qrow[1];
    float4 acca = make_float4(0.f, 0.f, 0.f, 0.f);
    float4 accb = make_float4(0.f, 0.f, 0.f, 0.f);
    float z = 0.f;
    int d = min(cnt[n * CS], CAP);
    int mySrc = (l < d) ? bucket[n * CAP + l] : 0;

    for (int i = 0; i < d; i += 4) {
        int eidx = i + es;
        bool valid = eidx < d;
        int src = __shfl(mySrc, valid ? eidx : i);
        const unsigned short* kr = KV + (size_t)src * KVS + 8 * q;
        ushort8_t ku = *(const ushort8_t*)kr;
        ushort8_t vu = *(const ushort8_t*)(kr + 128);
        float s = qa.x * b2f(ku[0]) + qa.y * b2f(ku[1]) +
                  qa.z * b2f(ku[2]) + qa.w * b2f(ku[3]) +
                  qb.x * b2f(ku[4]) + qb.y * b2f(ku[5]) +
                  qb.z * b2f(ku[6]) + qb.w * b2f(ku[7]);
        s += __shfl_xor(s, 1);     // 2-lane head reduce (16 dims)
        s *= 0.25f;                // / sqrt(16)
        s = fminf(fmaxf(s, -5.f), 5.f);
        s = __expf(s);
        if (!valid) s = 0.f;
        acca.x += b2f(vu[0]) * s; acca.y += b2f(vu[1]) * s;
        acca.z += b2f(vu[2]) * s; acca.w += b2f(vu[3]) * s;
        accb.x += b2f(vu[4]) * s; accb.y += b2f(vu[5]) * s;
        accb.z += b2f(vu[6]) * s; accb.w += b2f(vu[7]) * s;
        z += s;
    }
    // combine the 4 edge slots
#pragma unroll
    for (int m = 16; m <= 32; m <<= 1) {
        acca.x += __shfl_xor(acca.x, m); acca.y += __shfl_xor(acca.y, m);
        acca.z += __shfl_xor(acca.z, m); acca.w += __shfl_xor(acca.w, m);
        accb.x += __shfl_xor(accb.x, m); accb.y += __shfl_xor(accb.y, m);
        accb.z += __shfl_xor(accb.z, m); accb.w += __shfl_xor(accb.w, m);
        z += __shfl_xor(z, m);
    }
    if (es == 0) {
        float inv = 1.f / (z + 1e-6f);
        float4* orow = (float4*)(qout + (size_t)n * DD + 8 * q);
        orow[0] = make_float4(acca.x * inv, acca.y * inv, acca.z * inv, acca.w * inv);
        orow[1] = make_float4(accb.x * inv, accb.y * inv, accb.z * inv, accb.w * inv);
    }
}

extern "C" void kernel_launch(void* const* d_in, const int* in_sizes, int n_in,
                              void* d_out, int out_size, void* d_ws, size_t ws_size,
                              hipStream_t stream) {
    const float* x  = (const float*)d_in[0];
    const float* Wq = (const float*)d_in[1];
    const float* bq = (const float*)d_in[2];
    const float* Wk = (const float*)d_in[3];
    const float* bk = (const float*)d_in[4];
    const float* Wv = (const float*)d_in[5];
    const float* bv = (const float*)d_in[6];
    const int*   ei = (const int*)d_in[7];
    float* out = (float*)d_out;

    unsigned short* KV  = (unsigned short*)d_ws;          // NN*256 bf16 = 25.6 MB
    unsigned short* Wqb = KV + (size_t)NN * KVS;
    unsigned short* Wkb = Wqb + DD * DD;
    unsigned short* Wvb = Wkb + DD * DD;
    int* cnt    = (int*)(Wvb + DD * DD);                  // NN*CS ints = 3.2 MB
    int* bucket = cnt + (size_t)NN * CS;                  // NN*CAP = 12.8 MB

    hipMemsetAsync(cnt, 0, (size_t)NN * CS * sizeof(int), stream);
    prep<<<48, 256, 0, stream>>>(Wq, Wk, Wv, Wqb, Wkb, Wvb);
    mega<<<QB + SB, 256, 0, stream>>>(x, Wqb, bq, Wkb, bk, Wvb, bv, ei,
                                      out, KV, cnt, bucket);
    gather4<<<(NN + 3) / 4, 256, 0, stream>>>(KV, cnt, bucket, out);
}

// Round 9
// 144.825 us; speedup vs baseline: 1.1003x; 1.1003x over previous
//
#include <hip/hip_runtime.h>
#include <hip/hip_bf16.h>

#define NN 50000
#define EE 800000
#define DD 128
#define HH 8
#define CAP 64        // bucket capacity; P(deg>64) ~ 1e-55 for Binom(800K,1/50K)
#define KVS 256       // interleaved KV row stride (128 K + 128 V bf16)
#define QB 391        // ceil(50000/128) qkv blocks in mega
#define SB 196        // scatter blocks: 196*256*16 = 802816 >= 800000 edges

typedef short bf16x8 __attribute__((ext_vector_type(8)));
typedef float f32x4 __attribute__((ext_vector_type(4)));
typedef unsigned short ushort8_t __attribute__((ext_vector_type(8)));

__device__ __forceinline__ unsigned short f2b(float f) {
    unsigned int u = __builtin_bit_cast(unsigned int, f);
    unsigned int r = (u + 0x7FFFu + ((u >> 16) & 1u)) >> 16;
    return (unsigned short)r;
}
__device__ __forceinline__ float b2f(unsigned short u) {
    return __builtin_bit_cast(float, ((unsigned int)u) << 16);
}

// ---------------- prep: convert 3 weight matrices to bf16 + zero cnt ------
__global__ __launch_bounds__(256) void prep(const float* __restrict__ Wq,
                                            const float* __restrict__ Wk,
                                            const float* __restrict__ Wv,
                                            unsigned short* __restrict__ Wqb,
                                            unsigned short* __restrict__ Wkb,
                                            unsigned short* __restrict__ Wvb,
                                            int* __restrict__ cnt) {
    int bid = blockIdx.x, t = threadIdx.x;
    if (bid < 48) {
        int idx = bid * 256 + t;      // ushort4 unit; 4096 per matrix
        int mat = idx >> 12;
        int off = idx & 4095;
        const float* src = (mat == 0) ? Wq : (mat == 1) ? Wk : Wv;
        unsigned short* dst = (mat == 0) ? Wqb : (mat == 1) ? Wkb : Wvb;
        float4 v = ((const float4*)src)[off];
        ushort4 o;
        o.x = f2b(v.x); o.y = f2b(v.y); o.z = f2b(v.z); o.w = f2b(v.w);
        ((ushort4*)dst)[off] = o;
    } else {
        int i = (bid - 48) * 256 + t;
        if (i < NN) cnt[i] = 0;
    }
}

// ---------------- qkv helper: one matrix, two 16-row groups ---------------
// A-frag: lane l -> x[rg0 + (l&15)][ (l>>4)*8 + s*32 + j ]
// B-frag: lane l -> W[c0*16 + (l&15)][ (l>>4)*8 + s*32 + j ]
// D:      row = (l>>4)*4 + reg, col = l&15
template <int OUTKIND>  // 0 = fp32 out (stride DD), 1 = bf16 into KV (stride KVS)
__device__ __forceinline__ void qkv_mat(const unsigned short* __restrict__ W,
                                        const float* __restrict__ bias,
                                        float* __restrict__ qo,
                                        unsigned short* __restrict__ kvo,
                                        int kvoff,
                                        const bf16x8 a[2][4],
                                        int r0, int mrow, int kb,
                                        bool act0, bool act1) {
#pragma unroll
    for (int c0 = 0; c0 < 8; ++c0) {
        float bval = bias[c0 * 16 + mrow];
        const unsigned short* wr = W + (size_t)(c0 * 16 + mrow) * DD + kb * 8;
        bf16x8 w0 = *(const bf16x8*)(wr);
        bf16x8 w1 = *(const bf16x8*)(wr + 32);
        bf16x8 w2 = *(const bf16x8*)(wr + 64);
        bf16x8 w3 = *(const bf16x8*)(wr + 96);
#pragma unroll
        for (int g = 0; g < 2; ++g) {
            bool act = (g == 0) ? act0 : act1;
            f32x4 acc = {bval, bval, bval, bval};
            acc = __builtin_amdgcn_mfma_f32_16x16x32_bf16(a[g][0], w0, acc, 0, 0, 0);
            acc = __builtin_amdgcn_mfma_f32_16x16x32_bf16(a[g][1], w1, acc, 0, 0, 0);
            acc = __builtin_amdgcn_mfma_f32_16x16x32_bf16(a[g][2], w2, acc, 0, 0, 0);
            acc = __builtin_amdgcn_mfma_f32_16x16x32_bf16(a[g][3], w3, acc, 0, 0, 0);
            if (act) {
                int orow = r0 + 16 * g + kb * 4;
                int col = c0 * 16 + mrow;
                if (OUTKIND == 0) {
#pragma unroll
                    for (int r = 0; r < 4; ++r)
                        qo[(size_t)(orow + r) * DD + col] = acc[r];
                } else {
#pragma unroll
                    for (int r = 0; r < 4; ++r)
                        kvo[(size_t)(orow + r) * KVS + kvoff + col] = f2b(acc[r]);
                }
            }
        }
    }
}

// ---------------- mega: qkv (blocks 0..QB-1) + bucket scatter (rest) ------
__global__ __launch_bounds__(256) void mega(
    const float* __restrict__ x,
    const unsigned short* __restrict__ Wq, const float* __restrict__ bq,
    const unsigned short* __restrict__ Wk, const float* __restrict__ bk,
    const unsigned short* __restrict__ Wv, const float* __restrict__ bv,
    const int* __restrict__ ei,
    float* __restrict__ Qo, unsigned short* __restrict__ KV,
    int* __restrict__ cnt, int* __restrict__ bucket) {
    if (blockIdx.x < QB) {
        // ---- QKV projection, no LDS, no barriers ----
        const int wave = threadIdx.x >> 6;
        const int l = threadIdx.x & 63;
        const int r0 = blockIdx.x * 128 + wave * 32;
        const int mrow = l & 15;
        const int kb = l >> 4;
        const bool act0 = (r0 < NN);       // 50000 % 16 == 0
        const bool act1 = (r0 + 16 < NN);
        if (!act0) return;

        bf16x8 a[2][4];
#pragma unroll
        for (int g = 0; g < 2; ++g) {
            int row = (g == 0 || act1) ? (r0 + 16 * g + mrow) : r0;
            const float* xr = x + (size_t)row * DD + kb * 8;
#pragma unroll
            for (int s = 0; s < 4; ++s) {
                float4 f0 = *(const float4*)(xr + s * 32);
                float4 f1 = *(const float4*)(xr + s * 32 + 4);
                bf16x8 t;
                t[0] = (short)f2b(f0.x); t[1] = (short)f2b(f0.y);
                t[2] = (short)f2b(f0.z); t[3] = (short)f2b(f0.w);
                t[4] = (short)f2b(f1.x); t[5] = (short)f2b(f1.y);
                t[6] = (short)f2b(f1.z); t[7] = (short)f2b(f1.w);
                a[g][s] = t;
            }
        }
        qkv_mat<0>(Wq, bq, Qo, (unsigned short*)nullptr, 0, a, r0, mrow, kb, act0, act1);
        qkv_mat<1>(Wk, bk, (float*)nullptr, KV, 0,   a, r0, mrow, kb, act0, act1);
        qkv_mat<1>(Wv, bv, (float*)nullptr, KV, 128, a, r0, mrow, kb, act0, act1);
    } else {
        // ---- bucket scatter: 16 edges per thread, 16 atomics in flight ----
        int base4 = (blockIdx.x - QB) * 1024 + threadIdx.x;  // int4 unit
        int ss[16], ds[16];
#pragma unroll
        for (int j = 0; j < 4; ++j) {
            int idx = base4 + j * 256;
            int4 sv = make_int4(0, 0, 0, 0);
            int4 dv = make_int4(-1, -1, -1, -1);
            if (idx < EE / 4) {
                sv = ((const int4*)ei)[idx];
                dv = ((const int4*)(ei + EE))[idx];
            }
            ss[j * 4 + 0] = sv.x; ss[j * 4 + 1] = sv.y;
            ss[j * 4 + 2] = sv.z; ss[j * 4 + 3] = sv.w;
            ds[j * 4 + 0] = dv.x; ds[j * 4 + 1] = dv.y;
            ds[j * 4 + 2] = dv.z; ds[j * 4 + 3] = dv.w;
        }
        int p[16];
#pragma unroll
        for (int k = 0; k < 16; ++k)
            p[k] = (ds[k] >= 0) ? atomicAdd(&cnt[ds[k]], 1) : CAP;
#pragma unroll
        for (int k = 0; k < 16; ++k)
            if (p[k] < CAP) bucket[ds[k] * CAP + p[k]] = ss[k];
    }
}

// ---------------- gather: one wave per dst node, 4 edges in flight --------
// deg <= 64 => whole edge list in one wave-wide read.
// Lane l: edge slot es = l>>4, dim block q = l&15 (dims 8q..8q+7).
// Head = 16 dims = 2 lanes -> shfl_xor(.,1). Combine slots via xor 16,32.
__global__ __launch_bounds__(256) void gather4(const unsigned short* __restrict__ KV,
                                               const int* __restrict__ cnt,
                                               const int* __restrict__ bucket,
                                               float* __restrict__ qout) {
    int n = blockIdx.x * 4 + (threadIdx.x >> 6);
    if (n >= NN) return;
    int l = threadIdx.x & 63;
    int es = l >> 4;
    int q = l & 15;

    const float4* qrow = (const float4*)(qout + (size_t)n * DD + 8 * q);
    float4 qa = qrow[0], qb = qrow[1];
    float4 acca = make_float4(0.f, 0.f, 0.f, 0.f);
    float4 accb = make_float4(0.f, 0.f, 0.f, 0.f);
    float z = 0.f;
    int d = min(cnt[n], CAP);
    int mySrc = (l < d) ? bucket[n * CAP + l] : 0;

    for (int i = 0; i < d; i += 4) {
        int eidx = i + es;
        bool valid = eidx < d;
        int src = __shfl(mySrc, valid ? eidx : i);
        const unsigned short* kr = KV + (size_t)src * KVS + 8 * q;
        ushort8_t ku = *(const ushort8_t*)kr;
        ushort8_t vu = *(const ushort8_t*)(kr + 128);
        float s = qa.x * b2f(ku[0]) + qa.y * b2f(ku[1]) +
                  qa.z * b2f(ku[2]) + qa.w * b2f(ku[3]) +
                  qb.x * b2f(ku[4]) + qb.y * b2f(ku[5]) +
                  qb.z * b2f(ku[6]) + qb.w * b2f(ku[7]);
        s += __shfl_xor(s, 1);     // 2-lane head reduce (16 dims)
        s *= 0.25f;                // / sqrt(16)
        s = fminf(fmaxf(s, -5.f), 5.f);
        s = __expf(s);
        if (!valid) s = 0.f;
        acca.x += b2f(vu[0]) * s; acca.y += b2f(vu[1]) * s;
        acca.z += b2f(vu[2]) * s; acca.w += b2f(vu[3]) * s;
        accb.x += b2f(vu[4]) * s; accb.y += b2f(vu[5]) * s;
        accb.z += b2f(vu[6]) * s; accb.w += b2f(vu[7]) * s;
        z += s;
    }
    // combine the 4 edge slots
#pragma unroll
    for (int m = 16; m <= 32; m <<= 1) {
        acca.x += __shfl_xor(acca.x, m); acca.y += __shfl_xor(acca.y, m);
        acca.z += __shfl_xor(acca.z, m); acca.w += __shfl_xor(acca.w, m);
        accb.x += __shfl_xor(accb.x, m); accb.y += __shfl_xor(accb.y, m);
        accb.z += __shfl_xor(accb.z, m); accb.w += __shfl_xor(accb.w, m);
        z += __shfl_xor(z, m);
    }
    if (es == 0) {
        float inv = 1.f / (z + 1e-6f);
        float4* orow = (float4*)(qout + (size_t)n * DD + 8 * q);
        orow[0] = make_float4(acca.x * inv, acca.y * inv, acca.z * inv, acca.w * inv);
        orow[1] = make_float4(accb.x * inv, accb.y * inv, accb.z * inv, accb.w * inv);
    }
}

extern "C" void kernel_launch(void* const* d_in, const int* in_sizes, int n_in,
                              void* d_out, int out_size, void* d_ws, size_t ws_size,
                              hipStream_t stream) {
    const float* x  = (const float*)d_in[0];
    const float* Wq = (const float*)d_in[1];
    const float* bq = (const float*)d_in[2];
    const float* Wk = (const float*)d_in[3];
    const float* bk = (const float*)d_in[4];
    const float* Wv = (const float*)d_in[5];
    const float* bv = (const float*)d_in[6];
    const int*   ei = (const int*)d_in[7];
    float* out = (float*)d_out;

    unsigned short* KV  = (unsigned short*)d_ws;          // NN*256 bf16 = 25.6 MB
    unsigned short* Wqb = KV + (size_t)NN * KVS;
    unsigned short* Wkb = Wqb + DD * DD;
    unsigned short* Wvb = Wkb + DD * DD;
    int* cnt    = (int*)(Wvb + DD * DD);                  // NN
    int* bucket = cnt + NN;                               // NN*CAP = 12.8 MB

    prep<<<244, 256, 0, stream>>>(Wq, Wk, Wv, Wqb, Wkb, Wvb, cnt);
    mega<<<QB + SB, 256, 0, stream>>>(x, Wqb, bq, Wkb, bk, Wvb, bv, ei,
                                      out, KV, cnt, bucket);
    gather4<<<(NN + 3) / 4, 256, 0, stream>>>(KV, cnt, bucket, out);
}

// Round 10
// 120.437 us; speedup vs baseline: 1.3231x; 1.2025x over previous
//
#include <hip/hip_runtime.h>
#include <hip/hip_bf16.h>

#define NN 50000
#define EE 800000
#define DD 128
#define HH 8
#define CAP 64        // bucket capacity; P(deg>64) ~ 1e-55 for Binom(800K,1/50K)
#define KVS 256       // interleaved KV row stride (128 K + 128 V bf16)
#define QB 391        // ceil(50000/128) qkv blocks in mega
#define PAB 196       // phase-A partition blocks (4096 edges each)
#define NBIN 196      // dst bins (256 nodes each); dst>>8 in [0,196)
#define RSTRIDE 4096  // runbuf region stride (edges) per phase-A block

typedef short bf16x8 __attribute__((ext_vector_type(8)));
typedef float f32x4 __attribute__((ext_vector_type(4)));
typedef unsigned short ushort8_t __attribute__((ext_vector_type(8)));

__device__ __forceinline__ unsigned short f2b(float f) {
    unsigned int u = __builtin_bit_cast(unsigned int, f);
    unsigned int r = (u + 0x7FFFu + ((u >> 16) & 1u)) >> 16;
    return (unsigned short)r;
}
__device__ __forceinline__ float b2f(unsigned short u) {
    return __builtin_bit_cast(float, ((unsigned int)u) << 16);
}

// ---------------- prep: convert 3 weight matrices to bf16 -----------------
__global__ __launch_bounds__(256) void prep(const float* __restrict__ Wq,
                                            const float* __restrict__ Wk,
                                            const float* __restrict__ Wv,
                                            unsigned short* __restrict__ Wqb,
                                            unsigned short* __restrict__ Wkb,
                                            unsigned short* __restrict__ Wvb) {
    int idx = blockIdx.x * 256 + threadIdx.x;  // ushort4 unit; 4096 per matrix
    int mat = idx >> 12;
    int off = idx & 4095;
    const float* src = (mat == 0) ? Wq : (mat == 1) ? Wk : Wv;
    unsigned short* dst = (mat == 0) ? Wqb : (mat == 1) ? Wkb : Wvb;
    float4 v = ((const float4*)src)[off];
    ushort4 o;
    o.x = f2b(v.x); o.y = f2b(v.y); o.z = f2b(v.z); o.w = f2b(v.w);
    ((ushort4*)dst)[off] = o;
}

// ---------------- qkv helper: one matrix, two 16-row groups ---------------
// A-frag: lane l -> x[rg0 + (l&15)][ (l>>4)*8 + s*32 + j ]
// B-frag: lane l -> W[c0*16 + (l&15)][ (l>>4)*8 + s*32 + j ]
// D:      row = (l>>4)*4 + reg, col = l&15
template <int OUTKIND>  // 0 = fp32 out (stride DD), 1 = bf16 into KV (stride KVS)
__device__ __forceinline__ void qkv_mat(const unsigned short* __restrict__ W,
                                        const float* __restrict__ bias,
                                        float* __restrict__ qo,
                                        unsigned short* __restrict__ kvo,
                                        int kvoff,
                                        const bf16x8 a[2][4],
                                        int r0, int mrow, int kb,
                                        bool act0, bool act1) {
#pragma unroll
    for (int c0 = 0; c0 < 8; ++c0) {
        float bval = bias[c0 * 16 + mrow];
        const unsigned short* wr = W + (size_t)(c0 * 16 + mrow) * DD + kb * 8;
        bf16x8 w0 = *(const bf16x8*)(wr);
        bf16x8 w1 = *(const bf16x8*)(wr + 32);
        bf16x8 w2 = *(const bf16x8*)(wr + 64);
        bf16x8 w3 = *(const bf16x8*)(wr + 96);
#pragma unroll
        for (int g = 0; g < 2; ++g) {
            bool act = (g == 0) ? act0 : act1;
            f32x4 acc = {bval, bval, bval, bval};
            acc = __builtin_amdgcn_mfma_f32_16x16x32_bf16(a[g][0], w0, acc, 0, 0, 0);
            acc = __builtin_amdgcn_mfma_f32_16x16x32_bf16(a[g][1], w1, acc, 0, 0, 0);
            acc = __builtin_amdgcn_mfma_f32_16x16x32_bf16(a[g][2], w2, acc, 0, 0, 0);
            acc = __builtin_amdgcn_mfma_f32_16x16x32_bf16(a[g][3], w3, acc, 0, 0, 0);
            if (act) {
                int orow = r0 + 16 * g + kb * 4;
                int col = c0 * 16 + mrow;
                if (OUTKIND == 0) {
#pragma unroll
                    for (int r = 0; r < 4; ++r)
                        qo[(size_t)(orow + r) * DD + col] = acc[r];
                } else {
#pragma unroll
                    for (int r = 0; r < 4; ++r)
                        kvo[(size_t)(orow + r) * KVS + kvoff + col] = f2b(acc[r]);
                }
            }
        }
    }
}

// ---------------- mega: qkv (blocks 0..QB-1) + phase-A partition (rest) ---
// Phase A: 4096 edges/block; per-(block,bin) runs in a private 32KB region.
// Counting via LDS atomics, placement via LDS prefix scan. NO global atomics;
// scattered writes confined to the block's own 32KB window (L2-absorbed).
__global__ __launch_bounds__(256) void mega(
    const float* __restrict__ x,
    const unsigned short* __restrict__ Wq, const float* __restrict__ bq,
    const unsigned short* __restrict__ Wk, const float* __restrict__ bk,
    const unsigned short* __restrict__ Wv, const float* __restrict__ bv,
    const int* __restrict__ ei,
    float* __restrict__ Qo, unsigned short* __restrict__ KV,
    int2* __restrict__ runbuf, int* __restrict__ gcount,
    int* __restrict__ gstart) {
    __shared__ int lcnt[256];
    __shared__ int lpre[256];
    if (blockIdx.x < QB) {
        // ---- QKV projection, no LDS use, no barriers ----
        const int wave = threadIdx.x >> 6;
        const int l = threadIdx.x & 63;
        const int r0 = blockIdx.x * 128 + wave * 32;
        const int mrow = l & 15;
        const int kb = l >> 4;
        const bool act0 = (r0 < NN);       // 50000 % 16 == 0
        const bool act1 = (r0 + 16 < NN);
        if (!act0) return;

        bf16x8 a[2][4];
#pragma unroll
        for (int g = 0; g < 2; ++g) {
            int row = (g == 0 || act1) ? (r0 + 16 * g + mrow) : r0;
            const float* xr = x + (size_t)row * DD + kb * 8;
#pragma unroll
            for (int s = 0; s < 4; ++s) {
                float4 f0 = *(const float4*)(xr + s * 32);
                float4 f1 = *(const float4*)(xr + s * 32 + 4);
                bf16x8 t;
                t[0] = (short)f2b(f0.x); t[1] = (short)f2b(f0.y);
                t[2] = (short)f2b(f0.z); t[3] = (short)f2b(f0.w);
                t[4] = (short)f2b(f1.x); t[5] = (short)f2b(f1.y);
                t[6] = (short)f2b(f1.z); t[7] = (short)f2b(f1.w);
                a[g][s] = t;
            }
        }
        qkv_mat<0>(Wq, bq, Qo, (unsigned short*)nullptr, 0, a, r0, mrow, kb, act0, act1);
        qkv_mat<1>(Wk, bk, (float*)nullptr, KV, 0,   a, r0, mrow, kb, act0, act1);
        qkv_mat<1>(Wv, bv, (float*)nullptr, KV, 128, a, r0, mrow, kb, act0, act1);
    } else {
        // ---- phase A: bin partition, zero global atomics ----
        const int b = blockIdx.x - QB;   // 0..PAB-1
        const int t = threadIdx.x;
        lcnt[t] = 0;
        __syncthreads();

        int ss[16], dd[16], slot[16];
        int base4 = b * 1024 + t;        // int4 unit; 1024 per block
#pragma unroll
        for (int j = 0; j < 4; ++j) {
            int idx = base4 + j * 256;
            int4 sv = make_int4(0, 0, 0, 0);
            int4 dv = make_int4(-1, -1, -1, -1);
            if (idx < EE / 4) {
                sv = ((const int4*)ei)[idx];
                dv = ((const int4*)(ei + EE))[idx];
            }
            ss[j * 4 + 0] = sv.x; ss[j * 4 + 1] = sv.y;
            ss[j * 4 + 2] = sv.z; ss[j * 4 + 3] = sv.w;
            dd[j * 4 + 0] = dv.x; dd[j * 4 + 1] = dv.y;
            dd[j * 4 + 2] = dv.z; dd[j * 4 + 3] = dv.w;
        }
#pragma unroll
        for (int k = 0; k < 16; ++k)
            slot[k] = (dd[k] >= 0) ? atomicAdd(&lcnt[dd[k] >> 8], 1) : 0;
        __syncthreads();

        int myCnt = lcnt[t];
        lpre[t] = myCnt;
        __syncthreads();
        for (int off = 1; off < 256; off <<= 1) {
            int v = (t >= off) ? lpre[t - off] : 0;
            __syncthreads();
            lpre[t] += v;
            __syncthreads();
        }
        int excl = lpre[t] - myCnt;      // exclusive prefix for bin t
        __syncthreads();
        lpre[t] = excl;
        __syncthreads();

#pragma unroll
        for (int k = 0; k < 16; ++k) {
            if (dd[k] >= 0) {
                int pos = b * RSTRIDE + lpre[dd[k] >> 8] + slot[k];
                runbuf[pos] = make_int2(ss[k], dd[k]);
            }
        }
        if (t < NBIN) {                   // bin-major meta for phase-B coalescing
            gcount[t * PAB + b] = myCnt;
            gstart[t * PAB + b] = excl;
        }
    }
}

// ---------------- phase B: per-bin bucket build, LDS counters -------------
// Block c handles bin c (nodes c*256 .. c*256+255). Thread t drains phase-A
// block t's run for this bin. Bucket writes confined to a 64KB window.
__global__ __launch_bounds__(256) void binscatter(const int2* __restrict__ runbuf,
                                                  const int* __restrict__ gcount,
                                                  const int* __restrict__ gstart,
                                                  int* __restrict__ cnt,
                                                  int* __restrict__ bucket) {
    __shared__ int cnt2[256];
    const int c = blockIdx.x, t = threadIdx.x;
    cnt2[t] = 0;
    __syncthreads();
    if (t < PAB) {
        int start = gstart[c * PAB + t];
        int count = gcount[c * PAB + t];
        const int2* run = runbuf + t * RSTRIDE + start;
        for (int i = 0; i < count; ++i) {
            int2 e = run[i];
            int p = atomicAdd(&cnt2[e.y & 255], 1);
            if (p < CAP) bucket[e.y * CAP + p] = e.x;
        }
    }
    __syncthreads();
    int node = c * 256 + t;
    if (node < NN) cnt[node] = cnt2[t];
}

// ---------------- gather: one wave per dst node, 4 edges in flight --------
// deg <= 64 => whole edge list in one wave-wide read.
// Lane l: edge slot es = l>>4, dim block q = l&15 (dims 8q..8q+7).
// Head = 16 dims = 2 lanes -> shfl_xor(.,1). Combine slots via xor 16,32.
__global__ __launch_bounds__(256) void gather4(const unsigned short* __restrict__ KV,
                                               const int* __restrict__ cnt,
                                               const int* __restrict__ bucket,
                                               float* __restrict__ qout) {
    int n = blockIdx.x * 4 + (threadIdx.x >> 6);
    if (n >= NN) return;
    int l = threadIdx.x & 63;
    int es = l >> 4;
    int q = l & 15;

    const float4* qrow = (const float4*)(qout + (size_t)n * DD + 8 * q);
    float4 qa = qrow[0], qb = qrow[1];
    float4 acca = make_float4(0.f, 0.f, 0.f, 0.f);
    float4 accb = make_float4(0.f, 0.f, 0.f, 0.f);
    float z = 0.f;
    int d = min(cnt[n], CAP);
    int mySrc = (l < d) ? bucket[n * CAP + l] : 0;

    for (int i = 0; i < d; i += 4) {
        int eidx = i + es;
        bool valid = eidx < d;
        int src = __shfl(mySrc, valid ? eidx : i);
        const unsigned short* kr = KV + (size_t)src * KVS + 8 * q;
        ushort8_t ku = *(const ushort8_t*)kr;
        ushort8_t vu = *(const ushort8_t*)(kr + 128);
        float s = qa.x * b2f(ku[0]) + qa.y * b2f(ku[1]) +
                  qa.z * b2f(ku[2]) + qa.w * b2f(ku[3]) +
                  qb.x * b2f(ku[4]) + qb.y * b2f(ku[5]) +
                  qb.z * b2f(ku[6]) + qb.w * b2f(ku[7]);
        s += __shfl_xor(s, 1);     // 2-lane head reduce (16 dims)
        s *= 0.25f;                // / sqrt(16)
        s = fminf(fmaxf(s, -5.f), 5.f);
        s = __expf(s);
        if (!valid) s = 0.f;
        acca.x += b2f(vu[0]) * s; acca.y += b2f(vu[1]) * s;
        acca.z += b2f(vu[2]) * s; acca.w += b2f(vu[3]) * s;
        accb.x += b2f(vu[4]) * s; accb.y += b2f(vu[5]) * s;
        accb.z += b2f(vu[6]) * s; accb.w += b2f(vu[7]) * s;
        z += s;
    }
    // combine the 4 edge slots
#pragma unroll
    for (int m = 16; m <= 32; m <<= 1) {
        acca.x += __shfl_xor(acca.x, m); acca.y += __shfl_xor(acca.y, m);
        acca.z += __shfl_xor(acca.z, m); acca.w += __shfl_xor(acca.w, m);
        accb.x += __shfl_xor(accb.x, m); accb.y += __shfl_xor(accb.y, m);
        accb.z += __shfl_xor(accb.z, m); accb.w += __shfl_xor(accb.w, m);
        z += __shfl_xor(z, m);
    }
    if (es == 0) {
        float inv = 1.f / (z + 1e-6f);
        float4* orow = (float4*)(qout + (size_t)n * DD + 8 * q);
        orow[0] = make_float4(acca.x * inv, acca.y * inv, acca.z * inv, acca.w * inv);
        orow[1] = make_float4(accb.x * inv, accb.y * inv, accb.z * inv, accb.w * inv);
    }
}

extern "C" void kernel_launch(void* const* d_in, const int* in_sizes, int n_in,
                              void* d_out, int out_size, void* d_ws, size_t ws_size,
                              hipStream_t stream) {
    const float* x  = (const float*)d_in[0];
    const float* Wq = (const float*)d_in[1];
    const float* bq = (const float*)d_in[2];
    const float* Wk = (const float*)d_in[3];
    const float* bk = (const float*)d_in[4];
    const float* Wv = (const float*)d_in[5];
    const float* bv = (const float*)d_in[6];
    const int*   ei = (const int*)d_in[7];
    float* out = (float*)d_out;

    unsigned short* KV  = (unsigned short*)d_ws;          // NN*256 bf16 = 25.6 MB
    unsigned short* Wqb = KV + (size_t)NN * KVS;
    unsigned short* Wkb = Wqb + DD * DD;
    unsigned short* Wvb = Wkb + DD * DD;
    int* cnt    = (int*)(Wvb + DD * DD);                  // NN ints
    int* bucket = cnt + NN;                               // NN*CAP = 12.8 MB
    int2* runbuf = (int2*)(bucket + (size_t)NN * CAP);    // PAB*4096 int2 = 6.4 MB
    int* gcount = (int*)(runbuf + (size_t)PAB * RSTRIDE); // NBIN*PAB ints
    int* gstart = gcount + NBIN * PAB;

    prep<<<48, 256, 0, stream>>>(Wq, Wk, Wv, Wqb, Wkb, Wvb);
    mega<<<QB + PAB, 256, 0, stream>>>(x, Wqb, bq, Wkb, bk, Wvb, bv, ei,
                                       out, KV, runbuf, gcount, gstart);
    binscatter<<<NBIN, 256, 0, stream>>>(runbuf, gcount, gstart, cnt, bucket);
    gather4<<<(NN + 3) / 4, 256, 0, stream>>>(KV, cnt, bucket, out);
}

// Round 12
// 118.991 us; speedup vs baseline: 1.3391x; 1.0122x over previous
//
#include <hip/hip_runtime.h>
#include <hip/hip_bf16.h>

#define NN 50000
#define EE 800000
#define DD 128
#define HH 8
#define CAP 64        // bucket capacity; P(deg>64) ~ 1e-55 for Binom(800K,1/50K)
#define KVS 256       // interleaved KV row stride in shorts (128 K + 128 V bf16)
#define QB 391        // ceil(50000/128) qkv blocks in mega
#define PAB 196       // phase-A partition blocks (4096 edges each)
#define NBIN 196      // dst bins (256 nodes each)
#define RSTRIDE 4096  // runbuf region stride (edges) per phase-A block

typedef short bf16x8 __attribute__((ext_vector_type(8)));
typedef float f32x4 __attribute__((ext_vector_type(4)));
typedef unsigned short ushort8_t __attribute__((ext_vector_type(8)));

__device__ __forceinline__ unsigned short f2b(float f) {
    unsigned int u = __builtin_bit_cast(unsigned int, f);
    unsigned int r = (u + 0x7FFFu + ((u >> 16) & 1u)) >> 16;
    return (unsigned short)r;
}
__device__ __forceinline__ float b2f(unsigned short u) {
    return __builtin_bit_cast(float, ((unsigned int)u) << 16);
}

// ---------------- prep: convert 3 weight matrices to bf16 -----------------
__global__ __launch_bounds__(256) void prep(const float* __restrict__ Wq,
                                            const float* __restrict__ Wk,
                                            const float* __restrict__ Wv,
                                            unsigned short* __restrict__ Wqb,
                                            unsigned short* __restrict__ Wkb,
                                            unsigned short* __restrict__ Wvb) {
    int idx = blockIdx.x * 256 + threadIdx.x;  // ushort4 unit; 4096 per matrix
    int mat = idx >> 12;
    int off = idx & 4095;
    const float* src = (mat == 0) ? Wq : (mat == 1) ? Wk : Wv;
    unsigned short* dst = (mat == 0) ? Wqb : (mat == 1) ? Wkb : Wvb;
    float4 v = ((const float4*)src)[off];
    ushort4 o;
    o.x = f2b(v.x); o.y = f2b(v.y); o.z = f2b(v.z); o.w = f2b(v.w);
    ((ushort4*)dst)[off] = o;
}

// ---------------- qkv helper: one matrix, two 16-row groups ---------------
// A-frag: lane l -> x[rg0 + (l&15)][ (l>>4)*8 + s*32 + j ]
// B-frag: lane l -> W[c0*16 + (l&15)][ (l>>4)*8 + s*32 + j ]
// D:      row = (l>>4)*4 + reg, col = l&15
template <int OUTKIND>  // 0 = fp32 out (stride DD), 1 = bf16 into KV (stride KVS)
__device__ __forceinline__ void qkv_mat(const unsigned short* __restrict__ W,
                                        const float* __restrict__ bias,
                                        float* __restrict__ qo,
                                        unsigned short* __restrict__ kvo,
                                        int kvoff,
                                        const bf16x8 a[2][4],
                                        int r0, int mrow, int kb,
                                        bool act0, bool act1) {
#pragma unroll
    for (int c0 = 0; c0 < 8; ++c0) {
        float bval = bias[c0 * 16 + mrow];
        const unsigned short* wr = W + (size_t)(c0 * 16 + mrow) * DD + kb * 8;
        bf16x8 w0 = *(const bf16x8*)(wr);
        bf16x8 w1 = *(const bf16x8*)(wr + 32);
        bf16x8 w2 = *(const bf16x8*)(wr + 64);
        bf16x8 w3 = *(const bf16x8*)(wr + 96);
#pragma unroll
        for (int g = 0; g < 2; ++g) {
            bool act = (g == 0) ? act0 : act1;
            f32x4 acc = {bval, bval, bval, bval};
            acc = __builtin_amdgcn_mfma_f32_16x16x32_bf16(a[g][0], w0, acc, 0, 0, 0);
            acc = __builtin_amdgcn_mfma_f32_16x16x32_bf16(a[g][1], w1, acc, 0, 0, 0);
            acc = __builtin_amdgcn_mfma_f32_16x16x32_bf16(a[g][2], w2, acc, 0, 0, 0);
            acc = __builtin_amdgcn_mfma_f32_16x16x32_bf16(a[g][3], w3, acc, 0, 0, 0);
            if (act) {
                int orow = r0 + 16 * g + kb * 4;
                int col = c0 * 16 + mrow;
                if (OUTKIND == 0) {
#pragma unroll
                    for (int r = 0; r < 4; ++r)
                        qo[(size_t)(orow + r) * DD + col] = acc[r];
                } else {
#pragma unroll
                    for (int r = 0; r < 4; ++r)
                        kvo[(size_t)(orow + r) * KVS + kvoff + col] = f2b(acc[r]);
                }
            }
        }
    }
}

// ---------------- mega: qkv (blocks 0..QB-1) + phase-A partition (rest) ---
__global__ __launch_bounds__(256) void mega(
    const float* __restrict__ x,
    const unsigned short* __restrict__ Wq, const float* __restrict__ bq,
    const unsigned short* __restrict__ Wk, const float* __restrict__ bk,
    const unsigned short* __restrict__ Wv, const float* __restrict__ bv,
    const int* __restrict__ ei,
    float* __restrict__ Qo, unsigned short* __restrict__ KV,
    int* __restrict__ runbuf, int* __restrict__ gcount,
    int* __restrict__ gstart) {
    __shared__ int lcnt[256];
    __shared__ int lpre[256];
    if (blockIdx.x < QB) {
        // ---- QKV projection, no LDS use, no barriers ----
        const int wave = threadIdx.x >> 6;
        const int l = threadIdx.x & 63;
        const int r0 = blockIdx.x * 128 + wave * 32;
        const int mrow = l & 15;
        const int kb = l >> 4;
        const bool act0 = (r0 < NN);       // 50000 % 16 == 0
        const bool act1 = (r0 + 16 < NN);
        if (!act0) return;

        bf16x8 a[2][4];
#pragma unroll
        for (int g = 0; g < 2; ++g) {
            int row = (g == 0 || act1) ? (r0 + 16 * g + mrow) : r0;
            const float* xr = x + (size_t)row * DD + kb * 8;
#pragma unroll
            for (int s = 0; s < 4; ++s) {
                float4 f0 = *(const float4*)(xr + s * 32);
                float4 f1 = *(const float4*)(xr + s * 32 + 4);
                bf16x8 t;
                t[0] = (short)f2b(f0.x); t[1] = (short)f2b(f0.y);
                t[2] = (short)f2b(f0.z); t[3] = (short)f2b(f0.w);
                t[4] = (short)f2b(f1.x); t[5] = (short)f2b(f1.y);
                t[6] = (short)f2b(f1.z); t[7] = (short)f2b(f1.w);
                a[g][s] = t;
            }
        }
        qkv_mat<0>(Wq, bq, Qo, (unsigned short*)nullptr, 0, a, r0, mrow, kb, act0, act1);
        qkv_mat<1>(Wk, bk, (float*)nullptr, KV, 0,   a, r0, mrow, kb, act0, act1);
        qkv_mat<1>(Wv, bv, (float*)nullptr, KV, 128, a, r0, mrow, kb, act0, act1);
    } else {
        // ---- phase A: bin partition, zero global atomics ----
        const int b = blockIdx.x - QB;   // 0..PAB-1
        const int t = threadIdx.x;
        lcnt[t] = 0;
        __syncthreads();

        int ss[16], dd[16], slot[16];
        int base4 = b * 1024 + t;        // int4 unit
#pragma unroll
        for (int j = 0; j < 4; ++j) {
            int idx = base4 + j * 256;
            int4 sv = make_int4(0, 0, 0, 0);
            int4 dv = make_int4(-1, -1, -1, -1);
            if (idx < EE / 4) {
                sv = ((const int4*)ei)[idx];
                dv = ((const int4*)(ei + EE))[idx];
            }
            ss[j * 4 + 0] = sv.x; ss[j * 4 + 1] = sv.y;
            ss[j * 4 + 2] = sv.z; ss[j * 4 + 3] = sv.w;
            dd[j * 4 + 0] = dv.x; dd[j * 4 + 1] = dv.y;
            dd[j * 4 + 2] = dv.z; dd[j * 4 + 3] = dv.w;
        }
#pragma unroll
        for (int k = 0; k < 16; ++k)
            slot[k] = (dd[k] >= 0) ? atomicAdd(&lcnt[dd[k] >> 8], 1) : 0;
        __syncthreads();

        int myCnt = lcnt[t];
        lpre[t] = myCnt;
        __syncthreads();
        for (int off = 1; off < 256; off <<= 1) {
            int v = (t >= off) ? lpre[t - off] : 0;
            __syncthreads();
            lpre[t] += v;
            __syncthreads();
        }
        int excl = lpre[t] - myCnt;
        __syncthreads();
        lpre[t] = excl;
        __syncthreads();

#pragma unroll
        for (int k = 0; k < 16; ++k) {
            if (dd[k] >= 0) {
                int pos = b * RSTRIDE + lpre[dd[k] >> 8] + slot[k];
                runbuf[pos] = ss[k] | ((dd[k] & 255) << 16);  // src 16b | dloc 8b
            }
        }
        if (t < NBIN) {
            gcount[t * PAB + b] = myCnt;
            gstart[t * PAB + b] = excl;
        }
    }
}

// ---------------- phase B: per-bin bucket build, LDS counters -------------
__global__ __launch_bounds__(256) void binscatter(const int* __restrict__ runbuf,
                                                  const int* __restrict__ gcount,
                                                  const int* __restrict__ gstart,
                                                  int* __restrict__ cnt,
                                                  unsigned short* __restrict__ bucket) {
    __shared__ int cnt2[256];
    const int c = blockIdx.x, t = threadIdx.x;
    cnt2[t] = 0;
    __syncthreads();
    if (t < PAB) {
        int start = gstart[c * PAB + t];
        int count = gcount[c * PAB + t];
        const int* run = runbuf + t * RSTRIDE + start;
        for (int i = 0; i < count; ++i) {
            int e = run[i];
            int dloc = (e >> 16) & 255;
            int p = atomicAdd(&cnt2[dloc], 1);
            if (p < CAP)
                bucket[(size_t)(c * 256 + dloc) * CAP + p] = (unsigned short)(e & 0xFFFF);
        }
    }
    __syncthreads();
    int node = c * 256 + t;
    if (node < NN) cnt[node] = cnt2[t];
}

// ---------------- gather: head-per-lane, 8 edges in flight ----------------
// One wave per dst node. Lane l: edge slot es = l>>3, head h = l&7 (dims
// 16h..16h+15, 32B of K + 32B of V per edge). Full head dot per lane: NO
// cross-lane shuffle in the score chain. Slot combine via xor 8,16,32.
// Q fp32 lives in qout (= d_out); row overwritten in place with output.
__global__ __launch_bounds__(256) void gather8(const unsigned short* __restrict__ KV,
                                               const int* __restrict__ cnt,
                                               const unsigned short* __restrict__ bucket,
                                               float* __restrict__ qout) {
    int n = blockIdx.x * 4 + (threadIdx.x >> 6);
    if (n >= NN) return;
    int l = threadIdx.x & 63;
    int es = l >> 3;
    int h = l & 7;

    const float4* qp = (const float4*)(qout + (size_t)n * DD + 16 * h);
    float4 q0 = qp[0], q1 = qp[1], q2 = qp[2], q3 = qp[3];
    float qf[16] = {q0.x, q0.y, q0.z, q0.w, q1.x, q1.y, q1.z, q1.w,
                    q2.x, q2.y, q2.z, q2.w, q3.x, q3.y, q3.z, q3.w};

    float acc[16];
#pragma unroll
    for (int j = 0; j < 16; ++j) acc[j] = 0.f;
    float z = 0.f;

    int d = min(cnt[n], CAP);
    int mySrc = (l < d) ? (int)bucket[(size_t)n * CAP + l] : 0;

    for (int i = 0; i < d; i += 8) {
        int eidx = i + es;
        bool valid = eidx < d;
        int src = __shfl(mySrc, valid ? eidx : i);
        const unsigned short* kr = KV + (size_t)src * KVS + 16 * h;
        ushort8_t k0 = *(const ushort8_t*)kr;
        ushort8_t k1 = *(const ushort8_t*)(kr + 8);
        ushort8_t v0 = *(const ushort8_t*)(kr + 128);
        ushort8_t v1 = *(const ushort8_t*)(kr + 136);
        float s = qf[0] * b2f(k0[0]) + qf[1] * b2f(k0[1]) +
                  qf[2] * b2f(k0[2]) + qf[3] * b2f(k0[3]) +
                  qf[4] * b2f(k0[4]) + qf[5] * b2f(k0[5]) +
                  qf[6] * b2f(k0[6]) + qf[7] * b2f(k0[7]) +
                  qf[8] * b2f(k1[0]) + qf[9] * b2f(k1[1]) +
                  qf[10] * b2f(k1[2]) + qf[11] * b2f(k1[3]) +
                  qf[12] * b2f(k1[4]) + qf[13] * b2f(k1[5]) +
                  qf[14] * b2f(k1[6]) + qf[15] * b2f(k1[7]);
        s *= 0.25f;                // / sqrt(16)
        s = fminf(fmaxf(s, -5.f), 5.f);
        s = __expf(s);
        if (!valid) s = 0.f;
#pragma unroll
        for (int j = 0; j < 8; ++j) acc[j] += b2f(v0[j]) * s;
#pragma unroll
        for (int j = 0; j < 8; ++j) acc[8 + j] += b2f(v1[j]) * s;
        z += s;
    }
    // combine the 8 edge slots (lanes with equal h)
#pragma unroll
    for (int m = 8; m <= 32; m <<= 1) {
#pragma unroll
        for (int j = 0; j < 16; ++j) acc[j] += __shfl_xor(acc[j], m);
        z += __shfl_xor(z, m);
    }
    if (es == 0) {
        float inv = 1.f / (z + 1e-6f);
        float4* orow = (float4*)(qout + (size_t)n * DD + 16 * h);
#pragma unroll
        for (int j = 0; j < 4; ++j)
            orow[j] = make_float4(acc[4 * j] * inv, acc[4 * j + 1] * inv,
                                  acc[4 * j + 2] * inv, acc[4 * j + 3] * inv);
    }
}

extern "C" void kernel_launch(void* const* d_in, const int* in_sizes, int n_in,
                              void* d_out, int out_size, void* d_ws, size_t ws_size,
                              hipStream_t stream) {
    const float* x  = (const float*)d_in[0];
    const float* Wq = (const float*)d_in[1];
    const float* bq = (const float*)d_in[2];
    const float* Wk = (const float*)d_in[3];
    const float* bk = (const float*)d_in[4];
    const float* Wv = (const float*)d_in[5];
    const float* bv = (const float*)d_in[6];
    const int*   ei = (const int*)d_in[7];
    float* out = (float*)d_out;

    unsigned short* KV  = (unsigned short*)d_ws;          // NN*256 bf16 = 25.6 MB
    unsigned short* Wqb = KV + (size_t)NN * KVS;
    unsigned short* Wkb = Wqb + DD * DD;
    unsigned short* Wvb = Wkb + DD * DD;
    int* cnt = (int*)(Wvb + DD * DD);                     // NN ints
    unsigned short* bucket = (unsigned short*)(cnt + NN); // NN*CAP u16 = 6.4 MB
    int* runbuf = (int*)(bucket + (size_t)NN * CAP);      // PAB*4096 int = 3.2 MB
    int* gcount = runbuf + (size_t)PAB * RSTRIDE;         // NBIN*PAB
    int* gstart = gcount + NBIN * PAB;

    prep<<<48, 256, 0, stream>>>(Wq, Wk, Wv, Wqb, Wkb, Wvb);
    mega<<<QB + PAB, 256, 0, stream>>>(x, Wqb, bq, Wkb, bk, Wvb, bv, ei,
                                       out, KV, runbuf, gcount, gstart);
    binscatter<<<NBIN, 256, 0, stream>>>(runbuf, gcount, gstart, cnt, bucket);
    gather8<<<(NN + 3) / 4, 256, 0, stream>>>(KV, cnt, bucket, out);
}